// Round 6
// baseline (1216.094 us; speedup 1.0000x reference)
//
#include <hip/hip_runtime.h>

#define NTOK 49
#define CDIM 192
#define NHEAD 6
#define HDIM 32

typedef float f32x4 __attribute__((ext_vector_type(4), may_alias));
typedef short b16x8 __attribute__((ext_vector_type(8), may_alias));
typedef short b16x4 __attribute__((ext_vector_type(4), may_alias));

__device__ __forceinline__ f32x4 MFMA(b16x8 a, b16x8 b, f32x4 c) {
  return __builtin_amdgcn_mfma_f32_16x16x32_bf16(a, b, c, 0, 0, 0);
}

__device__ __forceinline__ short f2bf(float f) {
  unsigned u = __builtin_bit_cast(unsigned, f);
  u += 0x7FFFu + ((u >> 16) & 1u);  // round-to-nearest-even
  return (short)(u >> 16);
}

// XOR swizzles (granule 8 shorts = 16 B); all bijective per row.
__device__ __forceinline__ int swz(int r, int c) {   // [64][192]
  return r * 192 + (c ^ ((r & 7) << 3));
}
__device__ __forceinline__ int swz64(int r, int c) { // [64][64]
  return r * 64 + (c ^ ((r & 7) << 3));
}
__device__ __forceinline__ int qs(int r, int c) {    // [16][96]
  return r * 96 + (c ^ ((r & 3) << 3));
}
__device__ __forceinline__ int ps(int r, int c) {    // [16][32]
  return r * 32 + (c ^ ((r & 3) << 3));
}

// ---- prep 1: fp32 weights -> bf16 ws. Wq pre-scaled by D^-0.5 ----
__global__ void prep_w(const float* __restrict__ Wq, const float* __restrict__ Wkv,
                       const float* __restrict__ Wo, short* __restrict__ wsW) {
  const float scale = 0.17677669529663687f;
  int i = blockIdx.x * 256 + threadIdx.x;
  if (i >= 147456) return;
  float v;
  if (i < 36864)        v = Wq[i] * scale;
  else if (i < 110592)  v = Wkv[i - 36864];
  else                  v = Wo[i - 110592];
  wsW[i] = f2bf(v);
}

// ---- prep 2: rel-pos-bias [6][49][64] f32; k-pad (49..63) = -1e9 mask ----
__global__ void prep_bias(const float* __restrict__ rpb, float* __restrict__ bias_t) {
  int idx = blockIdx.x * 256 + threadIdx.x;
  if (idx >= NHEAD * NTOK * 64) return;
  int k = idx & 63;
  int q = (idx >> 6) % NTOK;
  int h = idx / (NTOK * 64);
  float v = -1e9f;
  if (k < NTOK) {
    int ci = (q / 7) * 13 + (q % 7);
    int jj = 48 - k;
    int cj = (jj / 7) * 13 + (jj % 7);
    v = rpb[(ci + cj) * NHEAD + h];
  }
  bias_t[idx] = v;
}

// Fused window-MSA: 1 window/block, 8 waves, 40960 B LDS -> 4 blocks/CU.
// LDS (shorts): X [0,12288) | KH2 [12288,16384) | VT2 [16384,20480).
// X: per-wave q-scratch -> kv bf16 stage -> x -> f32 store-bounce.
// KH2: per-pair kh -> per-wave P scratch.  VT2: per-pair vT.
// Swapped QK^T (mfma(K,Q)): lane l15 owns one q-row -> softmax = in-lane
// reduce + shfl_xor(16,32); k>=49 masked by bias-table -1e9 padding.
__global__ __attribute__((amdgpu_flat_work_group_size(512, 512),
                          amdgpu_waves_per_eu(8))) void wmsa_kernel(
    const float* __restrict__ qg, const float* __restrict__ kvg,
    const float* __restrict__ maskg, const float* __restrict__ bq,
    const float* __restrict__ bkv, const float* __restrict__ bo,
    const short* __restrict__ wsW, const float* __restrict__ bias_t,
    float* __restrict__ outg, int nW) {
  __shared__ short lds[20480];  // 40960 B exactly
  short* X = lds;
  short* KH2 = lds + 12288;
  short* VT2 = lds + 16384;
  float* BF = (float*)lds;      // epilogue bounce [32][192] f32 = 24576 B

  const int b = blockIdx.x;
  const int tid = threadIdx.x;
  const int w = tid >> 6;
  const int lane = tid & 63;
  const int l15 = lane & 15;
  const int lg = lane >> 4;
  const int R = w >> 1, hw = w & 1;
  const f32x4 zero4 = {0.f, 0.f, 0.f, 0.f};

  const short* WqB = wsW;
  const short* WkvB = wsW + 36864;
  const short* WoB = wsW + 110592;

  const float* qsrc = qg + (size_t)b * (NTOK * CDIM);
  const float* kvsrc = kvg + (size_t)b * (NTOK * CDIM);
  const float* maskw = maskg + (size_t)(b % nW) * (NTOK * NTOK);

  const int qrow = R * 16 + l15;
  const int qc = qrow > 48 ? 48 : qrow;  // clamped q (pad lanes -> row 48; outputs unused)

  // ================= 1. q-projection (fully per-wave) =================
  // Direct global q loads for rows R*16+l15; MFMA vs Wq; D->frag transpose
  // through per-wave scratch in X; result: aq[3] (heads hw, 2+hw, 4+hw).
  b16x8 aq6[6];
#pragma unroll
  for (int kk = 0; kk < 6; ++kk) {
    f32x4 lo = *(const f32x4*)(qsrc + qc * CDIM + kk * 32 + lg * 8);
    f32x4 hi = *(const f32x4*)(qsrc + qc * CDIM + kk * 32 + lg * 8 + 4);
    b16x8 a = {f2bf(lo[0]), f2bf(lo[1]), f2bf(lo[2]), f2bf(lo[3]),
               f2bf(hi[0]), f2bf(hi[1]), f2bf(hi[2]), f2bf(hi[3])};
    aq6[kk] = a;
  }
  f32x4 qacc[6];
#pragma unroll
  for (int t = 0; t < 6; ++t) qacc[t] = zero4;
#pragma unroll
  for (int t = 0; t < 6; ++t) {
    const int h = 2 * (t >> 1) + hw;
    const int col = h * 32 + (t & 1) * 16 + l15;
#pragma unroll
    for (int kk = 0; kk < 6; ++kk) {
      b16x8 bw = *(const b16x8*)(WqB + col * CDIM + kk * 32 + lg * 8);
      qacc[t] = MFMA(aq6[kk], bw, qacc[t]);
    }
  }
  short* qscr = X + w * 1536;  // per-wave [16][96]
#pragma unroll
  for (int t = 0; t < 6; ++t) {
    const int h = 2 * (t >> 1) + hw;
    const int col = h * 32 + (t & 1) * 16 + l15;
    const float bias = bq[col] * 0.17677669529663687f;
#pragma unroll
    for (int rr = 0; rr < 4; ++rr)
      qscr[qs(lg * 4 + rr, t * 16 + l15)] = f2bf(qacc[t][rr] + bias);
  }
  b16x8 aq[3];
#pragma unroll
  for (int pp = 0; pp < 3; ++pp)
    aq[pp] = *(const b16x8*)(qscr + qs(l15, pp * 32 + lg * 8));
  __syncthreads();  // B1: all aq extracted; X free

  // ================= 2. stage kv -> X (bf16, rows>=49 zeroed) =================
#pragma unroll
  for (int it = 0; it < 6; ++it) {
    int idx = tid + it * 512;
    int r = idx / 48, c4 = idx % 48;
    f32x4 v = (r < NTOK) ? *(const f32x4*)(kvsrc + r * CDIM + c4 * 4) : zero4;
    b16x4 o = {f2bf(v[0]), f2bf(v[1]), f2bf(v[2]), f2bf(v[3])};
    *(b16x4*)(X + swz(r, c4 * 4)) = o;
  }
  __syncthreads();  // B2: kv staged

  // ================= 3. head-pair loop =================
  b16x8 xbf[3];  // packed x per pair: [nv0 r0..3 | nv1 r0..3]
#pragma unroll
  for (int p = 0; p < 3; ++p) {
    // ---- kv-proj for pair p: 8 col-tiles (4 K + 4 V) x 4 m ----
    const int ct = w & 3;
    const int isV = w >> 2;
    const int colg = isV * CDIM + p * 64 + ct * 16 + l15;
    f32x4 acc[4];
#pragma unroll
    for (int m = 0; m < 4; ++m) acc[m] = zero4;
#pragma unroll
    for (int kk = 0; kk < 6; ++kk) {
      b16x8 bw = *(const b16x8*)(WkvB + colg * CDIM + kk * 32 + lg * 8);
#pragma unroll
      for (int m = 0; m < 4; ++m) {
        b16x8 a = *(const b16x8*)(X + swz(m * 16 + l15, kk * 32 + lg * 8));
        acc[m] = MFMA(a, bw, acc[m]);
      }
    }
    const float bias = bkv[colg];
    if (!isV) {  // K -> KH2[token][chan-in-pair]
#pragma unroll
      for (int m = 0; m < 4; ++m)
#pragma unroll
        for (int rr = 0; rr < 4; ++rr)
          KH2[swz64(m * 16 + lg * 4 + rr, ct * 16 + l15)] = f2bf(acc[m][rr] + bias);
    } else {  // V -> VT2[chan-in-pair][token]
#pragma unroll
      for (int m = 0; m < 4; ++m) {
        b16x4 o = {f2bf(acc[m][0] + bias), f2bf(acc[m][1] + bias),
                   f2bf(acc[m][2] + bias), f2bf(acc[m][3] + bias)};
        *(b16x4*)(VT2 + swz64(ct * 16 + l15, m * 16 + lg * 4)) = o;
      }
    }
    __syncthreads();  // Ba: kh2/vT2 ready

    // ---- QK^T (swapped): lane l15 = q-row, 16 k-values in regs ----
    const int h = 2 * p + hw;
    f32x4 Ls[4];
#pragma unroll
    for (int nt = 0; nt < 4; ++nt) {
      b16x8 bk = *(const b16x8*)(KH2 + swz64(nt * 16 + l15, hw * 32 + lg * 8));
      Ls[nt] = MFMA(bk, aq[p], zero4);
    }
    const float* bt = bias_t + (h * NTOK + qc) * 64;
#pragma unroll
    for (int nt = 0; nt < 4; ++nt) {
      f32x4 bb = *(const f32x4*)(bt + nt * 16 + lg * 4);
#pragma unroll
      for (int rr = 0; rr < 4; ++rr) {
        int kc = nt * 16 + lg * 4 + rr;
        kc = kc > 48 ? 48 : kc;  // k>=49: bias=-1e9 dominates
        Ls[nt][rr] += bb[rr] + maskw[qc * NTOK + kc];
      }
    }
    // ---- softmax: in-lane 16 + shfl_xor(16,32) ----
    float mx = Ls[0][0];
#pragma unroll
    for (int nt = 0; nt < 4; ++nt)
#pragma unroll
      for (int rr = 0; rr < 4; ++rr) mx = fmaxf(mx, Ls[nt][rr]);
    mx = fmaxf(mx, __shfl_xor(mx, 16));
    mx = fmaxf(mx, __shfl_xor(mx, 32));
    float sum = 0.f;
#pragma unroll
    for (int nt = 0; nt < 4; ++nt)
#pragma unroll
      for (int rr = 0; rr < 4; ++rr) {
        Ls[nt][rr] = __expf(Ls[nt][rr] - mx);
        sum += Ls[nt][rr];
      }
    sum += __shfl_xor(sum, 16);
    sum += __shfl_xor(sum, 32);
    const float inv = 1.f / sum;
    __syncthreads();  // Bb: all QK^T reads of KH2 done -> P scratch usable

    // ---- P -> per-wave scratch (KH2 region), two 32-k halves; PV ----
    short* Pscr = KH2 + w * 512;  // [16][32]
    b16x8 ap[2];
#pragma unroll
    for (int kkh = 0; kkh < 2; ++kkh) {
#pragma unroll
      for (int nth = 0; nth < 2; ++nth) {
        const int nt = 2 * kkh + nth;
        b16x4 o = {f2bf(Ls[nt][0] * inv), f2bf(Ls[nt][1] * inv),
                   f2bf(Ls[nt][2] * inv), f2bf(Ls[nt][3] * inv)};
        *(b16x4*)(Pscr + ps(l15, nth * 16 + lg * 4)) = o;
      }
      ap[kkh] = *(const b16x8*)(Pscr + ps(l15, lg * 8));
    }
    f32x4 xa[2] = {zero4, zero4};
#pragma unroll
    for (int kkh = 0; kkh < 2; ++kkh)
#pragma unroll
      for (int nv = 0; nv < 2; ++nv) {
        b16x8 bv = *(const b16x8*)(VT2 + swz64(hw * 32 + nv * 16 + l15, kkh * 32 + lg * 8));
        xa[nv] = MFMA(ap[kkh], bv, xa[nv]);
      }
    b16x8 xb = {f2bf(xa[0][0]), f2bf(xa[0][1]), f2bf(xa[0][2]), f2bf(xa[0][3]),
                f2bf(xa[1][0]), f2bf(xa[1][1]), f2bf(xa[1][2]), f2bf(xa[1][3])};
    xbf[p] = xb;
    __syncthreads();  // Bc: PV done; next pair may overwrite KH2/VT2
  }

  // ================= 4. x -> X (kv dead) =================
#pragma unroll
  for (int p = 0; p < 3; ++p) {
    const int h = 2 * p + hw;
#pragma unroll
    for (int nv = 0; nv < 2; ++nv)
#pragma unroll
      for (int rr = 0; rr < 4; ++rr)
        X[swz(R * 16 + lg * 4 + rr, h * 32 + nv * 16 + l15)] = xbf[p][nv * 4 + rr];
  }
  __syncthreads();  // B4: x complete

  // ================= 5. output projection: pid = t*8 + w =================
  f32x4 oacc[6];
#pragma unroll
  for (int t = 0; t < 6; ++t) oacc[t] = zero4;
#pragma unroll
  for (int t = 0; t < 6; ++t) {
    const int j = 2 * t + (w >> 2);
    const int m = w & 3;
    const int col = j * 16 + l15;
#pragma unroll
    for (int kk = 0; kk < 6; ++kk) {
      b16x8 a = *(const b16x8*)(X + swz(m * 16 + l15, kk * 32 + lg * 8));
      b16x8 bw = *(const b16x8*)(WoB + col * CDIM + kk * 32 + lg * 8);
      oacc[t] = MFMA(a, bw, oacc[t]);
    }
  }
  __syncthreads();  // B5: X reads done -> X = f32 bounce

  float* dst = outg + (size_t)b * (NTOK * CDIM);
  // pass 0: m in {0,1} -> rows 0..31
  if ((w & 3) < 2) {
#pragma unroll
    for (int t = 0; t < 6; ++t) {
      const int col = (2 * t + (w >> 2)) * 16 + l15;
      const float bias = bo[col];
#pragma unroll
      for (int rr = 0; rr < 4; ++rr)
        BF[((w & 3) * 16 + lg * 4 + rr) * 192 + col] = oacc[t][rr] + bias;
    }
  }
  __syncthreads();
#pragma unroll
  for (int it = 0; it < 3; ++it) {
    int idx = tid + it * 512;
    int row = idx / 48, c4 = idx % 48;
    *(f32x4*)(dst + row * CDIM + c4 * 4) = *(const f32x4*)(BF + row * 192 + c4 * 4);
  }
  __syncthreads();
  // pass 1: m in {2,3} -> rows 32..48
  if ((w & 3) >= 2) {
#pragma unroll
    for (int t = 0; t < 6; ++t) {
      const int col = (2 * t + (w >> 2)) * 16 + l15;
      const float bias = bo[col];
#pragma unroll
      for (int rr = 0; rr < 4; ++rr)
        BF[(((w & 3) - 2) * 16 + lg * 4 + rr) * 192 + col] = oacc[t][rr] + bias;
    }
  }
  __syncthreads();
#pragma unroll
  for (int it = 0; it < 2; ++it) {
    int idx = tid + it * 512;
    int row2 = idx / 48, c4 = idx % 48;
    if (row2 < 17)
      *(f32x4*)(dst + (32 + row2) * CDIM + c4 * 4) =
          *(const f32x4*)(BF + row2 * 192 + c4 * 4);
  }
}

extern "C" void kernel_launch(void* const* d_in, const int* in_sizes, int n_in,
                              void* d_out, int out_size, void* d_ws, size_t ws_size,
                              hipStream_t stream) {
  const float* q = (const float*)d_in[0];
  const float* kv = (const float*)d_in[1];
  const float* mask = (const float*)d_in[2];
  const float* Wq = (const float*)d_in[3];
  const float* bq = (const float*)d_in[4];
  const float* Wkv = (const float*)d_in[5];
  const float* bkv = (const float*)d_in[6];
  const float* Wo = (const float*)d_in[7];
  const float* bo = (const float*)d_in[8];
  const float* rpb = (const float*)d_in[9];
  short* wsW = (short*)d_ws;
  float* bias_t = (float*)((char*)d_ws + 294912);  // [6][49][64] f32, 75264 B

  const int B = in_sizes[0] / (NTOK * CDIM);
  const int nW = in_sizes[2] / (NTOK * NTOK);

  prep_w<<<576, 256, 0, stream>>>(Wq, Wkv, Wo, wsW);
  prep_bias<<<(NHEAD * NTOK * 64 + 255) / 256, 256, 0, stream>>>(rpb, bias_t);
  wmsa_kernel<<<B, 512, 0, stream>>>(q, kv, mask, bq, bkv, bo, wsW, bias_t,
                                     (float*)d_out, nW);
}

// Round 7
// 1102.872 us; speedup vs baseline: 1.1027x; 1.1027x over previous
//
#include <hip/hip_runtime.h>

#define NTOK 49
#define CDIM 192
#define NHEAD 6
#define HDIM 32

typedef float f32x4 __attribute__((ext_vector_type(4), may_alias));
typedef float f32x4u __attribute__((ext_vector_type(4), may_alias, aligned(4)));
typedef short b16x8 __attribute__((ext_vector_type(8), may_alias));
typedef short b16x4 __attribute__((ext_vector_type(4), may_alias));

__device__ __forceinline__ f32x4 MFMA(b16x8 a, b16x8 b, f32x4 c) {
  return __builtin_amdgcn_mfma_f32_16x16x32_bf16(a, b, c, 0, 0, 0);
}

__device__ __forceinline__ short f2bf(float f) {
  unsigned u = __builtin_bit_cast(unsigned, f);
  u += 0x7FFFu + ((u >> 16) & 1u);  // round-to-nearest-even
  return (short)(u >> 16);
}

// XOR swizzles (granule = 8 shorts = 16 B), bijective per row.
__device__ __forceinline__ int swz(int r, int c) {   // [64][192]
  return r * 192 + (c ^ ((r & 7) << 3));
}
__device__ __forceinline__ int swz64(int r, int c) { // [64][64]
  return r * 64 + (c ^ ((r & 7) << 3));
}
// [16][32] P scratch: mix row bits 0-1 AND 2-3 so rows ≡ mod 4 don't collide.
__device__ __forceinline__ int ps(int r, int c) {
  return r * 32 + (c ^ ((((r & 3) ^ ((r >> 2) & 3)) & 3) << 3));
}

// ---- prep 1: fp32 weights -> bf16 ws. Wq pre-scaled by D^-0.5 ----
__global__ void prep_w(const float* __restrict__ Wq, const float* __restrict__ Wkv,
                       const float* __restrict__ Wo, short* __restrict__ wsW) {
  const float scale = 0.17677669529663687f;
  int i = blockIdx.x * 256 + threadIdx.x;
  if (i >= 147456) return;
  float v;
  if (i < 36864)        v = Wq[i] * scale;
  else if (i < 110592)  v = Wkv[i - 36864];
  else                  v = Wo[i - 110592];
  wsW[i] = f2bf(v);
}

// ---- prep 2: rel-pos-bias [6][49][64] f32; k-pad (49..63) = -1e9 mask ----
__global__ void prep_bias(const float* __restrict__ rpb, float* __restrict__ bias_t) {
  int idx = blockIdx.x * 256 + threadIdx.x;
  if (idx >= NHEAD * NTOK * 64) return;
  int k = idx & 63;
  int q = (idx >> 6) % NTOK;
  int h = idx / (NTOK * 64);
  float v = -1e9f;
  if (k < NTOK) {
    int ci = (q / 7) * 13 + (q % 7);
    int jj = 48 - k;
    int cj = (jj / 7) * 13 + (jj % 7);
    v = rpb[(ci + cj) * NHEAD + h];
  }
  bias_t[idx] = v;
}

// Fused window-MSA: 1 window/block, 8 waves, 40960 B LDS.
// waves_per_eu(6) -> VGPR cap ~85 (R6's (8) forced a spill storm at cap 64).
// LDS (shorts): X [0,12288) | KH2 [12288,16384) | VT2 [16384,20480).
// X: per-wave qh scratch (before kv) -> kv bf16 stage -> x -> f32 bounce.
// KH2: per-pair kh -> per-wave P scratch.  VT2: per-pair vT.
// Swapped QK^T (mfma(K,Q)): lane l15 owns q-row -> in-lane softmax + 2 shfl.
__global__ __attribute__((amdgpu_flat_work_group_size(512, 512),
                          amdgpu_waves_per_eu(6))) void wmsa_kernel(
    const float* __restrict__ qg, const float* __restrict__ kvg,
    const float* __restrict__ maskg, const float* __restrict__ bq,
    const float* __restrict__ bkv, const float* __restrict__ bo,
    const short* __restrict__ wsW, const float* __restrict__ bias_t,
    float* __restrict__ outg, int nW) {
  __shared__ short lds[20480];  // 40960 B
  short* X = lds;
  short* KH2 = lds + 12288;
  short* VT2 = lds + 16384;
  float* BF = (float*)lds;      // epilogue bounce [32][196] f32 = 25088 B

  const int b = blockIdx.x;
  const int tid = threadIdx.x;
  const int w = tid >> 6;
  const int lane = tid & 63;
  const int l15 = lane & 15;
  const int lg = lane >> 4;
  const int R = w >> 1, hw = w & 1;
  const f32x4 zero4 = {0.f, 0.f, 0.f, 0.f};

  const short* WqB = wsW;
  const short* WkvB = wsW + 36864;
  const short* WoB = wsW + 110592;

  const float* qsrc = qg + (size_t)b * (NTOK * CDIM);
  const float* kvsrc = kvg + (size_t)b * (NTOK * CDIM);
  const float* maskw = maskg + (size_t)(b % nW) * (NTOK * NTOK);

  const int qrow = R * 16 + l15;
  const int qc = qrow > 48 ? 48 : qrow;  // pad lanes -> row 48 (outputs unused)

  // ============ 1. q-projection (per-wave; X free, kv not yet staged) ============
  b16x8 aq6[6];
#pragma unroll
  for (int kk = 0; kk < 6; ++kk) {
    f32x4 lo = *(const f32x4*)(qsrc + qc * CDIM + kk * 32 + lg * 8);
    f32x4 hi = *(const f32x4*)(qsrc + qc * CDIM + kk * 32 + lg * 8 + 4);
    b16x8 a = {f2bf(lo[0]), f2bf(lo[1]), f2bf(lo[2]), f2bf(lo[3]),
               f2bf(hi[0]), f2bf(hi[1]), f2bf(hi[2]), f2bf(hi[3])};
    aq6[kk] = a;
  }
  // rolling accumulator: one output tile at a time (low VGPR)
#pragma unroll
  for (int t = 0; t < 6; ++t) {
    const int col = (2 * (t >> 1) + hw) * 32 + (t & 1) * 16 + l15;
    f32x4 acc = zero4;
#pragma unroll
    for (int kk = 0; kk < 6; ++kk) {
      b16x8 bw = *(const b16x8*)(WqB + col * CDIM + kk * 32 + lg * 8);
      acc = MFMA(aq6[kk], bw, acc);
    }
    const float bias = bq[col] * 0.17677669529663687f;
#pragma unroll
    for (int rr = 0; rr < 4; ++rr)
      X[swz(R * 16 + lg * 4 + rr, hw * 96 + t * 16 + l15)] = f2bf(acc[rr] + bias);
  }
  // D->frag transpose readback (same wave wrote all 16 rows; in-order LDS)
  b16x8 aq[3];
#pragma unroll
  for (int p = 0; p < 3; ++p)
    aq[p] = *(const b16x8*)(X + swz(R * 16 + l15, hw * 96 + p * 32 + lg * 8));
  __syncthreads();  // B1: qh scratch reads done; X free

  // ============ 2. stage kv -> X (bf16, rows>=49 zeroed) ============
#pragma unroll
  for (int it = 0; it < 6; ++it) {
    int idx = tid + it * 512;
    int r = idx / 48, c4 = idx % 48;
    f32x4 v = (r < NTOK) ? *(const f32x4*)(kvsrc + r * CDIM + c4 * 4) : zero4;
    b16x4 o = {f2bf(v[0]), f2bf(v[1]), f2bf(v[2]), f2bf(v[3])};
    *(b16x4*)(X + swz(r, c4 * 4)) = o;
  }
  __syncthreads();  // B2: kv staged

  // ============ 3. head-pair loop ============
  b16x8 xbf[3];  // packed x per pair: [nv0 r0..3 | nv1 r0..3]
#pragma unroll
  for (int p = 0; p < 3; ++p) {
    // ---- kv-proj pair slice: wave w -> tile (isV = w>>2, ct = w&3) ----
    const int ct = w & 3;
    const int isV = w >> 2;
    const int colg = isV * CDIM + p * 64 + ct * 16 + l15;
    f32x4 acc[4];
#pragma unroll
    for (int m = 0; m < 4; ++m) acc[m] = zero4;
#pragma unroll
    for (int kk = 0; kk < 6; ++kk) {
      b16x8 bw = *(const b16x8*)(WkvB + colg * CDIM + kk * 32 + lg * 8);
#pragma unroll
      for (int m = 0; m < 4; ++m) {
        b16x8 a = *(const b16x8*)(X + swz(m * 16 + l15, kk * 32 + lg * 8));
        acc[m] = MFMA(a, bw, acc[m]);
      }
    }
    const float bias = bkv[colg];
    if (!isV) {  // K -> KH2[token][chan-in-pair]
#pragma unroll
      for (int m = 0; m < 4; ++m)
#pragma unroll
        for (int rr = 0; rr < 4; ++rr)
          KH2[swz64(m * 16 + lg * 4 + rr, ct * 16 + l15)] = f2bf(acc[m][rr] + bias);
    } else {  // V -> VT2[chan-in-pair][token]
#pragma unroll
      for (int m = 0; m < 4; ++m) {
        b16x4 o = {f2bf(acc[m][0] + bias), f2bf(acc[m][1] + bias),
                   f2bf(acc[m][2] + bias), f2bf(acc[m][3] + bias)};
        *(b16x4*)(VT2 + swz64(ct * 16 + l15, m * 16 + lg * 4)) = o;
      }
    }
    __syncthreads();  // Ba: kh2/vT2 ready

    // ---- QK^T (swapped): lane l15 = q-row ----
    const int h = 2 * p + hw;
    f32x4 Ls[4];
#pragma unroll
    for (int nt = 0; nt < 4; ++nt) {
      b16x8 bk = *(const b16x8*)(KH2 + swz64(nt * 16 + l15, hw * 32 + lg * 8));
      Ls[nt] = MFMA(bk, aq[p], zero4);
    }
    // bias (with -1e9 k-padding) + window mask, vectorized
    const float* bt = bias_t + (h * NTOK + qc) * 64;
#pragma unroll
    for (int nt = 0; nt < 4; ++nt) {
      f32x4 bb = *(const f32x4*)(bt + nt * 16 + lg * 4);
#pragma unroll
      for (int rr = 0; rr < 4; ++rr) Ls[nt][rr] += bb[rr];
    }
#pragma unroll
    for (int nt = 0; nt < 3; ++nt) {  // k = nt*16+lg*4 .. +3 <= 47
      f32x4 mm = *(const f32x4u*)(maskw + qc * NTOK + nt * 16 + lg * 4);
#pragma unroll
      for (int rr = 0; rr < 4; ++rr) Ls[nt][rr] += mm[rr];
    }
    if (lg == 0) Ls[3][0] += maskw[qc * NTOK + 48];  // k=48; k>=49 has -1e9 bias

    // ---- softmax: 15 in-lane + shfl_xor(16,32) ----
    float mx = Ls[0][0];
#pragma unroll
    for (int nt = 0; nt < 4; ++nt)
#pragma unroll
      for (int rr = 0; rr < 4; ++rr) mx = fmaxf(mx, Ls[nt][rr]);
    mx = fmaxf(mx, __shfl_xor(mx, 16));
    mx = fmaxf(mx, __shfl_xor(mx, 32));
    float sum = 0.f;
#pragma unroll
    for (int nt = 0; nt < 4; ++nt)
#pragma unroll
      for (int rr = 0; rr < 4; ++rr) {
        Ls[nt][rr] = __expf(Ls[nt][rr] - mx);
        sum += Ls[nt][rr];
      }
    sum += __shfl_xor(sum, 16);
    sum += __shfl_xor(sum, 32);
    const float inv = 1.f / sum;
    __syncthreads();  // Bb: QK^T reads of KH2 done -> P scratch usable

    // ---- P -> per-wave scratch (KH2 region), then PV ----
    short* Pscr = KH2 + w * 512;  // [16][32], ps-swizzled
    b16x8 ap[2];
#pragma unroll
    for (int kkh = 0; kkh < 2; ++kkh) {
#pragma unroll
      for (int nth = 0; nth < 2; ++nth) {
        const int nt = 2 * kkh + nth;
        b16x4 o = {f2bf(Ls[nt][0] * inv), f2bf(Ls[nt][1] * inv),
                   f2bf(Ls[nt][2] * inv), f2bf(Ls[nt][3] * inv)};
        *(b16x4*)(Pscr + ps(l15, nth * 16 + lg * 4)) = o;
      }
      ap[kkh] = *(const b16x8*)(Pscr + ps(l15, lg * 8));
    }
    f32x4 xa[2] = {zero4, zero4};
#pragma unroll
    for (int kkh = 0; kkh < 2; ++kkh)
#pragma unroll
      for (int nv = 0; nv < 2; ++nv) {
        b16x8 bv = *(const b16x8*)(VT2 + swz64(hw * 32 + nv * 16 + l15, kkh * 32 + lg * 8));
        xa[nv] = MFMA(ap[kkh], bv, xa[nv]);
      }
    b16x8 xb = {f2bf(xa[0][0]), f2bf(xa[0][1]), f2bf(xa[0][2]), f2bf(xa[0][3]),
                f2bf(xa[1][0]), f2bf(xa[1][1]), f2bf(xa[1][2]), f2bf(xa[1][3])};
    xbf[p] = xb;
    __syncthreads();  // Bc: PV done; next pair may overwrite KH2/VT2
  }

  // ============ 4. x -> X (kv dead; disjoint per-wave regions) ============
#pragma unroll
  for (int p = 0; p < 3; ++p) {
    const int h = 2 * p + hw;
#pragma unroll
    for (int nv = 0; nv < 2; ++nv)
#pragma unroll
      for (int rr = 0; rr < 4; ++rr)
        X[swz(R * 16 + lg * 4 + rr, h * 32 + nv * 16 + l15)] = xbf[p][nv * 4 + rr];
  }
  __syncthreads();  // B4: x complete

  // ============ 5. output projection ============
  f32x4 oacc[6];
#pragma unroll
  for (int t = 0; t < 6; ++t) oacc[t] = zero4;
#pragma unroll
  for (int t = 0; t < 6; ++t) {
    const int j = 2 * t + (w >> 2);
    const int m = w & 3;
    const int col = j * 16 + l15;
#pragma unroll
    for (int kk = 0; kk < 6; ++kk) {
      b16x8 a = *(const b16x8*)(X + swz(m * 16 + l15, kk * 32 + lg * 8));
      b16x8 bw = *(const b16x8*)(WoB + col * CDIM + kk * 32 + lg * 8);
      oacc[t] = MFMA(a, bw, oacc[t]);
    }
  }
  __syncthreads();  // B5: X reads done -> lds = f32 bounce [32][196]

  float* dst = outg + (size_t)b * (NTOK * CDIM);
  // pass 0: m in {0,1} -> token rows 0..31
  if ((w & 3) < 2) {
#pragma unroll
    for (int t = 0; t < 6; ++t) {
      const int col = (2 * t + (w >> 2)) * 16 + l15;
      const float bias = bo[col];
#pragma unroll
      for (int rr = 0; rr < 4; ++rr)
        BF[((w & 3) * 16 + lg * 4 + rr) * 196 + col] = oacc[t][rr] + bias;
    }
  }
  __syncthreads();
#pragma unroll
  for (int it = 0; it < 3; ++it) {
    int idx = tid + it * 512;
    int row = idx / 48, c4 = idx % 48;
    *(f32x4*)(dst + row * CDIM + c4 * 4) = *(const f32x4*)(BF + row * 196 + c4 * 4);
  }
  __syncthreads();
  // pass 1: m in {2,3} -> token rows 32..48
  if ((w & 3) >= 2) {
#pragma unroll
    for (int t = 0; t < 6; ++t) {
      const int col = (2 * t + (w >> 2)) * 16 + l15;
      const float bias = bo[col];
#pragma unroll
      for (int rr = 0; rr < 4; ++rr)
        BF[(((w & 3) - 2) * 16 + lg * 4 + rr) * 196 + col] = oacc[t][rr] + bias;
    }
  }
  __syncthreads();
#pragma unroll
  for (int it = 0; it < 2; ++it) {
    int idx = tid + it * 512;
    if (idx < 17 * 48) {
      int row2 = idx / 48, c4 = idx % 48;
      *(f32x4*)(dst + (32 + row2) * CDIM + c4 * 4) =
          *(const f32x4*)(BF + row2 * 196 + c4 * 4);
    }
  }
}

extern "C" void kernel_launch(void* const* d_in, const int* in_sizes, int n_in,
                              void* d_out, int out_size, void* d_ws, size_t ws_size,
                              hipStream_t stream) {
  const float* q = (const float*)d_in[0];
  const float* kv = (const float*)d_in[1];
  const float* mask = (const float*)d_in[2];
  const float* Wq = (const float*)d_in[3];
  const float* bq = (const float*)d_in[4];
  const float* Wkv = (const float*)d_in[5];
  const float* bkv = (const float*)d_in[6];
  const float* Wo = (const float*)d_in[7];
  const float* bo = (const float*)d_in[8];
  const float* rpb = (const float*)d_in[9];
  short* wsW = (short*)d_ws;
  float* bias_t = (float*)((char*)d_ws + 294912);  // [6][49][64] f32, 75264 B

  const int B = in_sizes[0] / (NTOK * CDIM);
  const int nW = in_sizes[2] / (NTOK * NTOK);

  prep_w<<<576, 256, 0, stream>>>(Wq, Wkv, Wo, wsW);
  prep_bias<<<(NHEAD * NTOK * 64 + 255) / 256, 256, 0, stream>>>(rpb, bias_t);
  wmsa_kernel<<<B, 512, 0, stream>>>(q, kv, mask, bq, bkv, bo, wsW, bias_t,
                                     (float*)d_out, nW);
}

// Round 8
// 965.277 us; speedup vs baseline: 1.2598x; 1.1425x over previous
//
#include <hip/hip_runtime.h>

#define NTOK 49
#define CDIM 192
#define NHEAD 6
#define HDIM 32

typedef float f32x4 __attribute__((ext_vector_type(4), may_alias));
typedef float f32x4u __attribute__((ext_vector_type(4), may_alias, aligned(4)));
typedef short b16x8 __attribute__((ext_vector_type(8), may_alias));
typedef short b16x4 __attribute__((ext_vector_type(4), may_alias));

__device__ __forceinline__ f32x4 MFMA(b16x8 a, b16x8 b, f32x4 c) {
  return __builtin_amdgcn_mfma_f32_16x16x32_bf16(a, b, c, 0, 0, 0);
}

__device__ __forceinline__ short f2bf(float f) {
  unsigned u = __builtin_bit_cast(unsigned, f);
  u += 0x7FFFu + ((u >> 16) & 1u);  // round-to-nearest-even
  return (short)(u >> 16);
}

// XOR swizzles (granule = 8 shorts = 16 B), bijective per row.
__device__ __forceinline__ int swz(int r, int c) {   // [64][192]
  return r * 192 + (c ^ ((r & 7) << 3));
}
__device__ __forceinline__ int swz64(int r, int c) { // [64][64]
  return r * 64 + (c ^ ((r & 7) << 3));
}
// [16][32] P scratch: mix row bits 0-1 AND 2-3 so rows ≡ mod 4 don't collide.
__device__ __forceinline__ int ps(int r, int c) {
  return r * 32 + (c ^ ((((r & 3) ^ ((r >> 2) & 3)) & 3) << 3));
}

// ---- prep 1: fp32 weights -> bf16 ws. Wq pre-scaled by D^-0.5 ----
__global__ void prep_w(const float* __restrict__ Wq, const float* __restrict__ Wkv,
                       const float* __restrict__ Wo, short* __restrict__ wsW) {
  const float scale = 0.17677669529663687f;
  int i = blockIdx.x * 256 + threadIdx.x;
  if (i >= 147456) return;
  float v;
  if (i < 36864)        v = Wq[i] * scale;
  else if (i < 110592)  v = Wkv[i - 36864];
  else                  v = Wo[i - 110592];
  wsW[i] = f2bf(v);
}

// ---- prep 2: rel-pos-bias [6][49][64] f32; k-pad (49..63) = -1e9 mask ----
__global__ void prep_bias(const float* __restrict__ rpb, float* __restrict__ bias_t) {
  int idx = blockIdx.x * 256 + threadIdx.x;
  if (idx >= NHEAD * NTOK * 64) return;
  int k = idx & 63;
  int q = (idx >> 6) % NTOK;
  int h = idx / (NTOK * 64);
  float v = -1e9f;
  if (k < NTOK) {
    int ci = (q / 7) * 13 + (q % 7);
    int jj = 48 - k;
    int cj = (jj / 7) * 13 + (jj % 7);
    v = rpb[(ci + cj) * NHEAD + h];
  }
  bias_t[idx] = v;
}

// Fused window-MSA: 1 window/block, 8 waves, 40960 B LDS.
// __launch_bounds__(512,4): empirically (R4/R5) yields VGPR=64 with NO spills;
// the waves_per_eu attr (R6/R7) forced VGPR 32-40 -> 1-1.6 GB spill traffic.
// At VGPR<=64, LDS 40KB -> 4 blocks/CU = 32 waves/CU.
// LDS (shorts): X [0,12288) | KH2 [12288,16384) | VT2 [16384,20480).
// X: per-wave qh scratch (before kv) -> kv bf16 stage -> x -> f32 bounce.
// KH2: per-pair kh -> per-wave P scratch.  VT2: per-pair vT.
// Swapped QK^T (mfma(K,Q)): lane l15 owns q-row -> in-lane softmax + 2 shfl.
__global__ __launch_bounds__(512, 4) void wmsa_kernel(
    const float* __restrict__ qg, const float* __restrict__ kvg,
    const float* __restrict__ maskg, const float* __restrict__ bq,
    const float* __restrict__ bkv, const float* __restrict__ bo,
    const short* __restrict__ wsW, const float* __restrict__ bias_t,
    float* __restrict__ outg, int nW) {
  __shared__ short lds[20480];  // 40960 B
  short* X = lds;
  short* KH2 = lds + 12288;
  short* VT2 = lds + 16384;
  float* BF = (float*)lds;      // epilogue bounce [32][196] f32 = 25088 B

  const int b = blockIdx.x;
  const int tid = threadIdx.x;
  const int w = tid >> 6;
  const int lane = tid & 63;
  const int l15 = lane & 15;
  const int lg = lane >> 4;
  const int R = w >> 1, hw = w & 1;
  const f32x4 zero4 = {0.f, 0.f, 0.f, 0.f};

  const short* WqB = wsW;
  const short* WkvB = wsW + 36864;
  const short* WoB = wsW + 110592;

  const float* qsrc = qg + (size_t)b * (NTOK * CDIM);
  const float* kvsrc = kvg + (size_t)b * (NTOK * CDIM);
  const float* maskw = maskg + (size_t)(b % nW) * (NTOK * NTOK);

  const int qrow = R * 16 + l15;
  const int qc = qrow > 48 ? 48 : qrow;  // pad lanes -> row 48 (outputs unused)

  // ============ 1. q-projection (per-wave; X free, kv not yet staged) ============
  b16x8 aq6[6];
#pragma unroll
  for (int kk = 0; kk < 6; ++kk) {
    f32x4 lo = *(const f32x4*)(qsrc + qc * CDIM + kk * 32 + lg * 8);
    f32x4 hi = *(const f32x4*)(qsrc + qc * CDIM + kk * 32 + lg * 8 + 4);
    b16x8 a = {f2bf(lo[0]), f2bf(lo[1]), f2bf(lo[2]), f2bf(lo[3]),
               f2bf(hi[0]), f2bf(hi[1]), f2bf(hi[2]), f2bf(hi[3])};
    aq6[kk] = a;
  }
  // rolling accumulator: one output tile at a time (low VGPR)
#pragma unroll
  for (int t = 0; t < 6; ++t) {
    const int col = (2 * (t >> 1) + hw) * 32 + (t & 1) * 16 + l15;
    f32x4 acc = zero4;
#pragma unroll
    for (int kk = 0; kk < 6; ++kk) {
      b16x8 bw = *(const b16x8*)(WqB + col * CDIM + kk * 32 + lg * 8);
      acc = MFMA(aq6[kk], bw, acc);
    }
    const float bias = bq[col] * 0.17677669529663687f;
#pragma unroll
    for (int rr = 0; rr < 4; ++rr)
      X[swz(R * 16 + lg * 4 + rr, hw * 96 + t * 16 + l15)] = f2bf(acc[rr] + bias);
  }
  // D->frag transpose readback (same wave wrote all 16 rows; in-order LDS)
  b16x8 aq[3];
#pragma unroll
  for (int p = 0; p < 3; ++p)
    aq[p] = *(const b16x8*)(X + swz(R * 16 + l15, hw * 96 + p * 32 + lg * 8));
  __syncthreads();  // B1: qh scratch reads done; X free

  // ============ 2. stage kv -> X (bf16, rows>=49 zeroed) ============
#pragma unroll
  for (int it = 0; it < 6; ++it) {
    int idx = tid + it * 512;
    int r = idx / 48, c4 = idx % 48;
    f32x4 v = (r < NTOK) ? *(const f32x4*)(kvsrc + r * CDIM + c4 * 4) : zero4;
    b16x4 o = {f2bf(v[0]), f2bf(v[1]), f2bf(v[2]), f2bf(v[3])};
    *(b16x4*)(X + swz(r, c4 * 4)) = o;
  }
  __syncthreads();  // B2: kv staged

  // ============ 3. head-pair loop ============
  b16x8 xbf[3];  // packed x per pair: [nv0 r0..3 | nv1 r0..3]
#pragma unroll
  for (int p = 0; p < 3; ++p) {
    // ---- kv-proj pair slice: wave w -> tile (isV = w>>2, ct = w&3) ----
    const int ct = w & 3;
    const int isV = w >> 2;
    const int colg = isV * CDIM + p * 64 + ct * 16 + l15;
    f32x4 acc[4];
#pragma unroll
    for (int m = 0; m < 4; ++m) acc[m] = zero4;
#pragma unroll
    for (int kk = 0; kk < 6; ++kk) {
      b16x8 bw = *(const b16x8*)(WkvB + colg * CDIM + kk * 32 + lg * 8);
#pragma unroll
      for (int m = 0; m < 4; ++m) {
        b16x8 a = *(const b16x8*)(X + swz(m * 16 + l15, kk * 32 + lg * 8));
        acc[m] = MFMA(a, bw, acc[m]);
      }
    }
    const float bias = bkv[colg];
    if (!isV) {  // K -> KH2[token][chan-in-pair]
#pragma unroll
      for (int m = 0; m < 4; ++m)
#pragma unroll
        for (int rr = 0; rr < 4; ++rr)
          KH2[swz64(m * 16 + lg * 4 + rr, ct * 16 + l15)] = f2bf(acc[m][rr] + bias);
    } else {  // V -> VT2[chan-in-pair][token]
#pragma unroll
      for (int m = 0; m < 4; ++m) {
        b16x4 o = {f2bf(acc[m][0] + bias), f2bf(acc[m][1] + bias),
                   f2bf(acc[m][2] + bias), f2bf(acc[m][3] + bias)};
        *(b16x4*)(VT2 + swz64(ct * 16 + l15, m * 16 + lg * 4)) = o;
      }
    }
    __syncthreads();  // Ba: kh2/vT2 ready

    // ---- QK^T (swapped): lane l15 = q-row ----
    const int h = 2 * p + hw;
    f32x4 Ls[4];
#pragma unroll
    for (int nt = 0; nt < 4; ++nt) {
      b16x8 bk = *(const b16x8*)(KH2 + swz64(nt * 16 + l15, hw * 32 + lg * 8));
      Ls[nt] = MFMA(bk, aq[p], zero4);
    }
    // bias (with -1e9 k-padding) + window mask, vectorized
    const float* bt = bias_t + (h * NTOK + qc) * 64;
#pragma unroll
    for (int nt = 0; nt < 4; ++nt) {
      f32x4 bb = *(const f32x4*)(bt + nt * 16 + lg * 4);
#pragma unroll
      for (int rr = 0; rr < 4; ++rr) Ls[nt][rr] += bb[rr];
    }
#pragma unroll
    for (int nt = 0; nt < 3; ++nt) {  // k = nt*16+lg*4 .. +3 <= 47
      f32x4 mm = *(const f32x4u*)(maskw + qc * NTOK + nt * 16 + lg * 4);
#pragma unroll
      for (int rr = 0; rr < 4; ++rr) Ls[nt][rr] += mm[rr];
    }
    if (lg == 0) Ls[3][0] += maskw[qc * NTOK + 48];  // k=48; k>=49 has -1e9 bias

    // ---- softmax: 15 in-lane + shfl_xor(16,32) ----
    float mx = Ls[0][0];
#pragma unroll
    for (int nt = 0; nt < 4; ++nt)
#pragma unroll
      for (int rr = 0; rr < 4; ++rr) mx = fmaxf(mx, Ls[nt][rr]);
    mx = fmaxf(mx, __shfl_xor(mx, 16));
    mx = fmaxf(mx, __shfl_xor(mx, 32));
    float sum = 0.f;
#pragma unroll
    for (int nt = 0; nt < 4; ++nt)
#pragma unroll
      for (int rr = 0; rr < 4; ++rr) {
        Ls[nt][rr] = __expf(Ls[nt][rr] - mx);
        sum += Ls[nt][rr];
      }
    sum += __shfl_xor(sum, 16);
    sum += __shfl_xor(sum, 32);
    const float inv = 1.f / sum;
    __syncthreads();  // Bb: QK^T reads of KH2 done -> P scratch usable

    // ---- P -> per-wave scratch (KH2 region), then PV ----
    short* Pscr = KH2 + w * 512;  // [16][32], ps-swizzled
    b16x8 ap[2];
#pragma unroll
    for (int kkh = 0; kkh < 2; ++kkh) {
#pragma unroll
      for (int nth = 0; nth < 2; ++nth) {
        const int nt = 2 * kkh + nth;
        b16x4 o = {f2bf(Ls[nt][0] * inv), f2bf(Ls[nt][1] * inv),
                   f2bf(Ls[nt][2] * inv), f2bf(Ls[nt][3] * inv)};
        *(b16x4*)(Pscr + ps(l15, nth * 16 + lg * 4)) = o;
      }
      ap[kkh] = *(const b16x8*)(Pscr + ps(l15, lg * 8));
    }
    f32x4 xa[2] = {zero4, zero4};
#pragma unroll
    for (int kkh = 0; kkh < 2; ++kkh)
#pragma unroll
      for (int nv = 0; nv < 2; ++nv) {
        b16x8 bv = *(const b16x8*)(VT2 + swz64(hw * 32 + nv * 16 + l15, kkh * 32 + lg * 8));
        xa[nv] = MFMA(ap[kkh], bv, xa[nv]);
      }
    b16x8 xb = {f2bf(xa[0][0]), f2bf(xa[0][1]), f2bf(xa[0][2]), f2bf(xa[0][3]),
                f2bf(xa[1][0]), f2bf(xa[1][1]), f2bf(xa[1][2]), f2bf(xa[1][3])};
    xbf[p] = xb;
    __syncthreads();  // Bc: PV done; next pair may overwrite KH2/VT2
  }

  // ============ 4. x -> X (kv dead; disjoint per-wave regions) ============
#pragma unroll
  for (int p = 0; p < 3; ++p) {
    const int h = 2 * p + hw;
#pragma unroll
    for (int nv = 0; nv < 2; ++nv)
#pragma unroll
      for (int rr = 0; rr < 4; ++rr)
        X[swz(R * 16 + lg * 4 + rr, h * 32 + nv * 16 + l15)] = xbf[p][nv * 4 + rr];
  }
  __syncthreads();  // B4: x complete

  // ============ 5. output projection ============
  f32x4 oacc[6];
#pragma unroll
  for (int t = 0; t < 6; ++t) oacc[t] = zero4;
#pragma unroll
  for (int t = 0; t < 6; ++t) {
    const int j = 2 * t + (w >> 2);
    const int m = w & 3;
    const int col = j * 16 + l15;
#pragma unroll
    for (int kk = 0; kk < 6; ++kk) {
      b16x8 a = *(const b16x8*)(X + swz(m * 16 + l15, kk * 32 + lg * 8));
      b16x8 bw = *(const b16x8*)(WoB + col * CDIM + kk * 32 + lg * 8);
      oacc[t] = MFMA(a, bw, oacc[t]);
    }
  }
  __syncthreads();  // B5: X reads done -> lds = f32 bounce [32][196]

  float* dst = outg + (size_t)b * (NTOK * CDIM);
  // pass 0: m in {0,1} -> token rows 0..31
  if ((w & 3) < 2) {
#pragma unroll
    for (int t = 0; t < 6; ++t) {
      const int col = (2 * t + (w >> 2)) * 16 + l15;
      const float bias = bo[col];
#pragma unroll
      for (int rr = 0; rr < 4; ++rr)
        BF[((w & 3) * 16 + lg * 4 + rr) * 196 + col] = oacc[t][rr] + bias;
    }
  }
  __syncthreads();
#pragma unroll
  for (int it = 0; it < 3; ++it) {
    int idx = tid + it * 512;
    int row = idx / 48, c4 = idx % 48;
    *(f32x4*)(dst + row * CDIM + c4 * 4) = *(const f32x4*)(BF + row * 196 + c4 * 4);
  }
  __syncthreads();
  // pass 1: m in {2,3} -> token rows 32..48
  if ((w & 3) >= 2) {
#pragma unroll
    for (int t = 0; t < 6; ++t) {
      const int col = (2 * t + (w >> 2)) * 16 + l15;
      const float bias = bo[col];
#pragma unroll
      for (int rr = 0; rr < 4; ++rr)
        BF[(((w & 3) - 2) * 16 + lg * 4 + rr) * 196 + col] = oacc[t][rr] + bias;
    }
  }
  __syncthreads();
#pragma unroll
  for (int it = 0; it < 2; ++it) {
    int idx = tid + it * 512;
    if (idx < 17 * 48) {
      int row2 = idx / 48, c4 = idx % 48;
      *(f32x4*)(dst + (32 + row2) * CDIM + c4 * 4) =
          *(const f32x4*)(BF + row2 * 196 + c4 * 4);
    }
  }
}

extern "C" void kernel_launch(void* const* d_in, const int* in_sizes, int n_in,
                              void* d_out, int out_size, void* d_ws, size_t ws_size,
                              hipStream_t stream) {
  const float* q = (const float*)d_in[0];
  const float* kv = (const float*)d_in[1];
  const float* mask = (const float*)d_in[2];
  const float* Wq = (const float*)d_in[3];
  const float* bq = (const float*)d_in[4];
  const float* Wkv = (const float*)d_in[5];
  const float* bkv = (const float*)d_in[6];
  const float* Wo = (const float*)d_in[7];
  const float* bo = (const float*)d_in[8];
  const float* rpb = (const float*)d_in[9];
  short* wsW = (short*)d_ws;
  float* bias_t = (float*)((char*)d_ws + 294912);  // [6][49][64] f32, 75264 B

  const int B = in_sizes[0] / (NTOK * CDIM);
  const int nW = in_sizes[2] / (NTOK * NTOK);

  prep_w<<<576, 256, 0, stream>>>(Wq, Wkv, Wo, wsW);
  prep_bias<<<(NHEAD * NTOK * 64 + 255) / 256, 256, 0, stream>>>(rpb, bias_t);
  wmsa_kernel<<<B, 512, 0, stream>>>(q, kv, mask, bq, bkv, bo, wsW, bias_t,
                                     (float*)d_out, nW);
}